// Round 1
// baseline (62.231 us; speedup 1.0000x reference)
//
#include <hip/hip_runtime.h>
#include <math.h>

#define WAVES_PER_BLOCK 4
#define MAXP 32

__global__ __launch_bounds__(256) void pfn_kernel(
    const float* __restrict__ voxels,
    const int*   __restrict__ num_points,
    const int*   __restrict__ coords,
    const float* __restrict__ W,
    const float* __restrict__ gamma,
    const float* __restrict__ beta,
    const float* __restrict__ rmean,
    const float* __restrict__ rvar,
    float*       __restrict__ out,
    int N)
{
    __shared__ float lds[WAVES_PER_BLOCK][MAXP * 4];

    const int tid  = threadIdx.x;
    const int lane = tid & 63;
    const int wid  = tid >> 6;
    const int pillar = blockIdx.x * WAVES_PER_BLOCK + wid;

    // ---- per-lane (= per output channel) constants ----
    const int d = lane;
    const float w0 = W[0*64+d], w1 = W[1*64+d], w2 = W[2*64+d];
    const float w3 = W[3*64+d], w4 = W[4*64+d], w5 = W[5*64+d];
    const float w6 = W[6*64+d], w7 = W[7*64+d], w8 = W[8*64+d];
    const float inv   = gamma[d] * rsqrtf(rvar[d] + 1e-3f);
    const float shift = fmaf(-rmean[d], inv, beta[d]);
    const float A  = (w0 + w4 + w7) * inv;   // coeff of x
    const float B  = (w1 + w5 + w8) * inv;   // coeff of y
    const float C  = (w2 + w6) * inv;        // coeff of z
    const float Dk = w3 * inv;               // coeff of w (intensity)
    const float P4 = w4 * inv, P5 = w5 * inv, P6 = w6 * inv;
    const float P7 = w7 * inv, P8 = w8 * inv;

    const bool active = (pillar < N);

    // ---- stage this wave's pillar (32 pts x float4 = 512B) into LDS ----
    if (active) {
        const float2* src = (const float2*)(voxels + (size_t)pillar * (MAXP * 4));
        ((float2*)lds[wid])[lane] = src[lane];   // 64 lanes x 8B, coalesced
    }
    __syncthreads();
    if (!active) return;

    const float4* pts = (const float4*)lds[wid];

    // ---- xyz sums over ALL 32 points (reference sums padding too) ----
    float4 mine = pts[lane & 31];   // both 32-halves read same points
    float sx = mine.x, sy = mine.y, sz = mine.z;
    #pragma unroll
    for (int msk = 1; msk < 32; msk <<= 1) {
        sx += __shfl_xor(sx, msk);
        sy += __shfl_xor(sy, msk);
        sz += __shfl_xor(sz, msk);
    }

    const int   np  = num_points[pillar];
    const float rnf = 1.0f / (float)np;
    const float cx  = fmaf((float)coords[pillar*3+0], 0.2f, 0.1f);     // VX/2
    const float cy  = fmaf((float)coords[pillar*3+1], 0.2f, -25.5f);   // VY/2 - 25.6
    const float E   = shift - (sx*P4 + sy*P5 + sz*P6) * rnf - cx*P7 - cy*P8;

    // masked points contribute exactly `shift` (features zeroed pre-matmul)
    float m = (np < MAXP) ? shift : -INFINITY;

    #pragma unroll 4
    for (int p = 0; p < np; ++p) {        // np is wave-uniform: no divergence
        const float4 q = pts[p];          // broadcast ds_read_b128
        float v = fmaf(q.x, A, E);
        v = fmaf(q.y, B, v);
        v = fmaf(q.z, C, v);
        v = fmaf(q.w, Dk, v);
        m = fmaxf(m, v);
    }

    out[(size_t)pillar * 64 + d] = fmaxf(m, 0.0f);   // relu(max) == max(relu)
}

extern "C" void kernel_launch(void* const* d_in, const int* in_sizes, int n_in,
                              void* d_out, int out_size, void* d_ws, size_t ws_size,
                              hipStream_t stream) {
    const float* voxels     = (const float*)d_in[0];
    const int*   num_points = (const int*)  d_in[1];
    const int*   coords     = (const int*)  d_in[2];
    const float* W          = (const float*)d_in[3];
    const float* gamma      = (const float*)d_in[4];
    const float* beta       = (const float*)d_in[5];
    const float* rmean      = (const float*)d_in[6];
    const float* rvar       = (const float*)d_in[7];
    float*       out        = (float*)d_out;

    const int N = in_sizes[1];  // num_points has one entry per pillar
    const int blocks = (N + WAVES_PER_BLOCK - 1) / WAVES_PER_BLOCK;
    pfn_kernel<<<blocks, 256, 0, stream>>>(voxels, num_points, coords, W,
                                           gamma, beta, rmean, rvar, out, N);
}